// Round 1
// baseline (642.546 us; speedup 1.0000x reference)
//
#include <hip/hip_runtime.h>
#include <hip/hip_bf16.h>
#include <math.h>

#define D 64

__device__ __forceinline__ float bcast(float v, int l) {
    return __uint_as_float(__builtin_amdgcn_readlane(__float_as_uint(v), l));
}

__device__ __forceinline__ float gelu_exact(float x) {
    return 0.5f * x * (1.0f + erff(x * 0.70710678118654752f));
}

// K1: per node: LayerNorm -> xn; q = xn@Wq^T + bq; qks = q@Wks; qkd = q@Wkd;
// bqs = q.bks; bqd = q.bkd
__global__ __launch_bounds__(256) void node_pre(
    const float* __restrict__ x, const float* __restrict__ gamma, const float* __restrict__ beta,
    const float* __restrict__ Wq, const float* __restrict__ bq,
    const float* __restrict__ Wks, const float* __restrict__ bks,
    const float* __restrict__ Wkd, const float* __restrict__ bkd,
    float* __restrict__ xn, float* __restrict__ qks, float* __restrict__ qkd,
    float* __restrict__ bqs, float* __restrict__ bqd, int N)
{
    __shared__ float WqT[64 * 65];   // WqT[j*65+i] = Wq[i][j]
    __shared__ float WksL[64 * 65];  // WksL[i*65+j] = Wks[i][j]
    __shared__ float WkdL[64 * 65];
    for (int idx = threadIdx.x; idx < 4096; idx += 256) {
        int i = idx >> 6, j = idx & 63;
        WqT[j * 65 + i] = Wq[idx];
        WksL[i * 65 + j] = Wks[idx];
        WkdL[i * 65 + j] = Wkd[idx];
    }
    __syncthreads();
    const int lane = threadIdx.x & 63;
    const int wave = blockIdx.x * (blockDim.x >> 6) + (threadIdx.x >> 6);
    const int nwaves = gridDim.x * (blockDim.x >> 6);
    const float g = gamma[lane], b = beta[lane];
    const float bqv = bq[lane], bksv = bks[lane], bkdv = bkd[lane];

    for (int n = wave; n < N; n += nwaves) {
        float xv = x[(long)n * D + lane];
        float s = xv;
        #pragma unroll
        for (int o = 32; o; o >>= 1) s += __shfl_xor(s, o);
        float mu = s * (1.0f / 64.0f);
        float d0 = xv - mu;
        float s2 = d0 * d0;
        #pragma unroll
        for (int o = 32; o; o >>= 1) s2 += __shfl_xor(s2, o);
        float var = s2 * (1.0f / 64.0f);
        float xh = d0 * rsqrtf(var + 1e-5f) * g + b;
        xn[(long)n * D + lane] = xh;

        // q_i = bq_i + sum_j Wq[i][j] * xh_j   (lane = i)
        float q = bqv;
        #pragma unroll
        for (int j = 0; j < 64; ++j) q = fmaf(bcast(xh, j), WqT[j * 65 + lane], q);

        // qks_j = sum_i q_i * Wks[i][j]        (lane = j)
        float aks = 0.f, akd = 0.f;
        #pragma unroll
        for (int i = 0; i < 64; ++i) {
            float qi = bcast(q, i);
            aks = fmaf(qi, WksL[i * 65 + lane], aks);
            akd = fmaf(qi, WkdL[i * 65 + lane], akd);
        }
        qks[(long)n * D + lane] = aks;
        qkd[(long)n * D + lane] = akd;

        float ps = q * bksv, pd = q * bkdv;
        #pragma unroll
        for (int o = 32; o; o >>= 1) { ps += __shfl_xor(ps, o); pd += __shfl_xor(pd, o); }
        if (lane == 0) { bqs[n] = ps; bqd[n] = pd; }
    }
}

// K2: per edge (one wave per edge):
//   xt = gelu([xn[src], t] @ Wt^T + bt) + temporal_enc(t)
//   att = (xt . qsel[dst] + bqsel[dst]) / 8 ;  ex = exp(att)   (no max-shift; invariant)
//   atomic: Asel[dst] += ex*xt ; denom_sel[dst] += ex
__global__ __launch_bounds__(256) void edge_pass(
    const int* __restrict__ ei, const float* __restrict__ et, const float* __restrict__ esame,
    const float* __restrict__ Wt, const float* __restrict__ bt,
    const float* __restrict__ xn, const float* __restrict__ qks, const float* __restrict__ qkd,
    const float* __restrict__ bqs, const float* __restrict__ bqd,
    float* __restrict__ As, float* __restrict__ Ad,
    float* __restrict__ den_s, float* __restrict__ den_d, int E)
{
    const int lane = threadIdx.x & 63;
    const int wave = blockIdx.x * (blockDim.x >> 6) + (threadIdx.x >> 6);
    const int nwaves = gridDim.x * (blockDim.x >> 6);

    // weight row i of Wt (65 entries) in registers, lane = i
    float wt[65];
    #pragma unroll
    for (int j = 0; j < 65; ++j) wt[j] = Wt[lane * 65 + j];
    const float btv = bt[lane];
    // temporal encoding divisor for this lane
    const float divt = expf(-9.210340371976184f * (float)(2 * (lane >> 1)) * (1.0f / 64.0f));

    for (int e = wave; e < E; e += nwaves) {
        int src = ei[e];
        int dst = ei[E + e];
        float t = et[e];
        float same = esame[e];

        float xj = xn[(long)src * D + lane];
        float acc = fmaf(t, wt[64], btv);
        #pragma unroll
        for (int j = 0; j < 64; ++j) acc = fmaf(bcast(xj, j), wt[j], acc);
        float h = gelu_exact(acc);
        float p = t * 200.0f * divt;
        float te = (lane & 1) ? cosf(p) : sinf(p);
        float xt = h + te;

        bool s1 = same > 0.5f;  // edge_same is exactly 0.0 or 1.0
        const float* qsel = s1 ? qks : qkd;
        float a = xt * qsel[(long)dst * D + lane];
        #pragma unroll
        for (int o = 32; o; o >>= 1) a += __shfl_xor(a, o);
        float att = (a + (s1 ? bqs[dst] : bqd[dst])) * 0.125f;
        float ex = expf(att);

        float* Asel = s1 ? As : Ad;
        atomicAdd(&Asel[(long)dst * D + lane], ex * xt);
        if (lane == 0) atomicAdd(s1 ? &den_s[dst] : &den_d[dst], ex);
    }
}

// K3: per node: aggr = (As/den)@Wvs^T + (den_s/den)*bvs + (Ad/den)@Wvd^T + (den_d/den)*bvd
//     out = x + gelu(aggr)
__global__ __launch_bounds__(256) void node_post(
    const float* __restrict__ x,
    const float* __restrict__ Wvs, const float* __restrict__ bvs,
    const float* __restrict__ Wvd, const float* __restrict__ bvd,
    const float* __restrict__ As, const float* __restrict__ Ad,
    const float* __restrict__ den_s, const float* __restrict__ den_d,
    float* __restrict__ out, int N)
{
    __shared__ float WvsT[64 * 65];
    __shared__ float WvdT[64 * 65];
    for (int idx = threadIdx.x; idx < 4096; idx += 256) {
        int i = idx >> 6, j = idx & 63;
        WvsT[j * 65 + i] = Wvs[idx];
        WvdT[j * 65 + i] = Wvd[idx];
    }
    __syncthreads();
    const int lane = threadIdx.x & 63;
    const int wave = blockIdx.x * (blockDim.x >> 6) + (threadIdx.x >> 6);
    const int nwaves = gridDim.x * (blockDim.x >> 6);
    const float bvsv = bvs[lane], bvdv = bvd[lane];

    for (int n = wave; n < N; n += nwaves) {
        float dsv = den_s[n], ddv = den_d[n];
        float inv = 1.0f / (dsv + ddv + 1e-16f);
        float as = As[(long)n * D + lane] * inv;
        float ad = Ad[(long)n * D + lane] * inv;
        float acc = bvsv * (dsv * inv) + bvdv * (ddv * inv);
        #pragma unroll
        for (int j = 0; j < 64; ++j) {
            acc = fmaf(bcast(as, j), WvsT[j * 65 + lane], acc);
            acc = fmaf(bcast(ad, j), WvdT[j * 65 + lane], acc);
        }
        out[(long)n * D + lane] = x[(long)n * D + lane] + gelu_exact(acc);
    }
}

extern "C" void kernel_launch(void* const* d_in, const int* in_sizes, int n_in,
                              void* d_out, int out_size, void* d_ws, size_t ws_size,
                              hipStream_t stream) {
    const float* x        = (const float*)d_in[0];
    const int*   ei       = (const int*)d_in[1];
    const float* et       = (const float*)d_in[2];
    // d_in[3] = x_time (unused by the reference)
    const float* esame    = (const float*)d_in[4];
    const float* ln_gamma = (const float*)d_in[5];
    const float* ln_beta  = (const float*)d_in[6];
    const float* Wt  = (const float*)d_in[7];
    const float* bt  = (const float*)d_in[8];
    const float* Wq  = (const float*)d_in[9];
    const float* bq  = (const float*)d_in[10];
    const float* Wks = (const float*)d_in[11];
    const float* bks = (const float*)d_in[12];
    const float* Wkd = (const float*)d_in[13];
    const float* bkd = (const float*)d_in[14];
    const float* Wvs = (const float*)d_in[15];
    const float* bvs = (const float*)d_in[16];
    const float* Wvd = (const float*)d_in[17];
    const float* bvd = (const float*)d_in[18];
    float* out = (float*)d_out;

    const int N = in_sizes[0] / D;       // 50000
    const int E = in_sizes[2];           // 800000

    float* w = (float*)d_ws;
    float* xn   = w; w += (long)N * D;
    float* qks  = w; w += (long)N * D;
    float* qkd  = w; w += (long)N * D;
    float* bqs  = w; w += N;
    float* bqd  = w; w += N;
    float* As   = w; w += (long)N * D;
    float* Ad   = w; w += (long)N * D;
    float* dens = w; w += N;
    float* dend = w; w += N;

    // zero the accumulators (As, Ad, dens, dend are contiguous)
    hipMemsetAsync(As, 0, ((size_t)N * D * 2 + (size_t)N * 2) * sizeof(float), stream);

    node_pre<<<512, 256, 0, stream>>>(x, ln_gamma, ln_beta, Wq, bq, Wks, bks, Wkd, bkd,
                                      xn, qks, qkd, bqs, bqd, N);
    edge_pass<<<2048, 256, 0, stream>>>(ei, et, esame, Wt, bt, xn, qks, qkd, bqs, bqd,
                                        As, Ad, dens, dend, E);
    node_post<<<512, 256, 0, stream>>>(x, Wvs, bvs, Wvd, bvd, As, Ad, dens, dend, out, N);
}

// Round 2
// 424.559 us; speedup vs baseline: 1.5134x; 1.5134x over previous
//
#include <hip/hip_runtime.h>
#include <hip/hip_bf16.h>
#include <math.h>

#define D 64

typedef __attribute__((ext_vector_type(8))) short bf16x8;
typedef __attribute__((ext_vector_type(4))) float f32x4;

__device__ __forceinline__ float bcast(float v, int l) {
    return __uint_as_float(__builtin_amdgcn_readlane(__float_as_uint(v), l));
}

__device__ __forceinline__ float gelu_exact(float x) {
    return 0.5f * x * (1.0f + erff(x * 0.70710678118654752f));
}

__device__ __forceinline__ unsigned short f2bf(float v) {
    __hip_bfloat16 h = __float2bfloat16(v);
    return *(unsigned short*)&h;
}

// Pack Wt (f32 [64][65]) into bf16 B-fragments for mfma_f32_16x16x32_bf16.
// Fragment f = ntile*2 + kk (ntile=0..3 over output dims, kk=0..1 over k).
// Lane L holds B[k = kk*32 + (L>>4)*8 + j][n = ntile*16 + (L&15)] = Wt[n][k].
__global__ void prep_wt(const float* __restrict__ Wt, unsigned short* __restrict__ WtB) {
    int lane = threadIdx.x & 63;
    int c = lane & 15, quad = lane >> 4;
    for (int f = 0; f < 8; ++f) {
        int ntile = f >> 1, kk = f & 1;
        for (int j = 0; j < 8; ++j) {
            float v = Wt[(ntile * 16 + c) * 65 + kk * 32 + quad * 8 + j];
            WtB[(f * 64 + lane) * 8 + j] = f2bf(v);
        }
    }
}

// K1: per node: LayerNorm -> xnb (bf16); q = xn@Wq^T + bq; qks = q@Wks; qkd = q@Wkd;
// bqs = q.bks; bqd = q.bkd
__global__ __launch_bounds__(256) void node_pre(
    const float* __restrict__ x, const float* __restrict__ gamma, const float* __restrict__ beta,
    const float* __restrict__ Wq, const float* __restrict__ bq,
    const float* __restrict__ Wks, const float* __restrict__ bks,
    const float* __restrict__ Wkd, const float* __restrict__ bkd,
    unsigned short* __restrict__ xnb, float* __restrict__ qks, float* __restrict__ qkd,
    float* __restrict__ bqs, float* __restrict__ bqd, int N)
{
    __shared__ float WqT[64 * 65];   // WqT[j*65+i] = Wq[i][j]
    __shared__ float WksL[64 * 65];  // WksL[i*65+j] = Wks[i][j]
    __shared__ float WkdL[64 * 65];
    for (int idx = threadIdx.x; idx < 4096; idx += 256) {
        int i = idx >> 6, j = idx & 63;
        WqT[j * 65 + i] = Wq[idx];
        WksL[i * 65 + j] = Wks[idx];
        WkdL[i * 65 + j] = Wkd[idx];
    }
    __syncthreads();
    const int lane = threadIdx.x & 63;
    const int wave = blockIdx.x * (blockDim.x >> 6) + (threadIdx.x >> 6);
    const int nwaves = gridDim.x * (blockDim.x >> 6);
    const float g = gamma[lane], b = beta[lane];
    const float bqv = bq[lane], bksv = bks[lane], bkdv = bkd[lane];

    for (int n = wave; n < N; n += nwaves) {
        float xv = x[(long)n * D + lane];
        float s = xv;
        #pragma unroll
        for (int o = 32; o; o >>= 1) s += __shfl_xor(s, o);
        float mu = s * (1.0f / 64.0f);
        float d0 = xv - mu;
        float s2 = d0 * d0;
        #pragma unroll
        for (int o = 32; o; o >>= 1) s2 += __shfl_xor(s2, o);
        float var = s2 * (1.0f / 64.0f);
        float xh = d0 * rsqrtf(var + 1e-5f) * g + b;
        xnb[(long)n * D + lane] = f2bf(xh);

        // q_i = bq_i + sum_j Wq[i][j] * xh_j   (lane = i)
        float q = bqv;
        #pragma unroll
        for (int j = 0; j < 64; ++j) q = fmaf(bcast(xh, j), WqT[j * 65 + lane], q);

        // qks_j = sum_i q_i * Wks[i][j]        (lane = j)
        float aks = 0.f, akd = 0.f;
        #pragma unroll
        for (int i = 0; i < 64; ++i) {
            float qi = bcast(q, i);
            aks = fmaf(qi, WksL[i * 65 + lane], aks);
            akd = fmaf(qi, WkdL[i * 65 + lane], akd);
        }
        qks[(long)n * D + lane] = aks;
        qkd[(long)n * D + lane] = akd;

        float ps = q * bksv, pd = q * bkdv;
        #pragma unroll
        for (int o = 32; o; o >>= 1) { ps += __shfl_xor(ps, o); pd += __shfl_xor(pd, o); }
        if (lane == 0) { bqs[n] = ps; bqd[n] = pd; }
    }
}

// K2 (MFMA): 16 edges per wave-iteration.
//   A[m][k] = xnb[src[m]][k] (bf16), B[k][n] = Wt[n][k] (prepacked), C = f32.
//   xt[m][n] = gelu(C + t*Wt[n][64] + bt[n]) + te(t, n)
//   att = xt . qsel[dst] + bq_sel[dst];  ex = exp(att/8)   (max-shift-free softmax)
//   atomic: Asel[dst] += ex*xt ; denom_sel[dst] += ex
__global__ __launch_bounds__(256) void edge_pass(
    const int* __restrict__ ei, const float* __restrict__ et, const float* __restrict__ esame,
    const unsigned short* __restrict__ xnb, const unsigned short* __restrict__ WtB,
    const float* __restrict__ Wt, const float* __restrict__ bt,
    const float* __restrict__ qks, const float* __restrict__ qkd,
    const float* __restrict__ bqs, const float* __restrict__ bqd,
    float* __restrict__ As, float* __restrict__ Ad,
    float* __restrict__ den_s, float* __restrict__ den_d, int E)
{
    const int lane = threadIdx.x & 63;
    const int c = lane & 15;     // n within tile (epilogue), edge slot (loads)
    const int quad = lane >> 4;  // k-group (A/B), row-group (C)
    const int wave = blockIdx.x * (blockDim.x >> 6) + (threadIdx.x >> 6);
    const int nwaves = gridDim.x * (blockDim.x >> 6);

    // B fragments (held in registers for the whole kernel)
    bf16x8 bfrag[8];
    #pragma unroll
    for (int f = 0; f < 8; ++f)
        bfrag[f] = *(const bf16x8*)(WtB + (f * 64 + lane) * 8);

    // per-lane epilogue constants, one per n-tile (dim = tile*16 + c)
    float btc[4], w64c[4], dva[4];
    #pragma unroll
    for (int tile = 0; tile < 4; ++tile) {
        int dim = tile * 16 + c;
        btc[tile] = bt[dim];
        w64c[tile] = Wt[dim * 65 + 64];
        dva[tile] = 200.0f * expf(-9.210340371976184f * (float)(2 * (dim >> 1)) * (1.0f / 64.0f));
    }
    const bool use_cos = (c & 1);

    for (long e0 = (long)wave * 16; e0 < E; e0 += (long)nwaves * 16) {
        int eL = (int)e0 + c;
        int eLc = eL < E ? eL : E - 1;
        int srcL = ei[eLc];
        int dstL = ei[E + eLc];
        float tL = et[eLc];
        float sameL = esame[eLc];

        // A fragments: 8 contiguous bf16 from row src[c] at k = kk*32 + quad*8
        const unsigned short* arow = xnb + (long)srcL * D + quad * 8;
        bf16x8 a0 = *(const bf16x8*)(arow);
        bf16x8 a1 = *(const bf16x8*)(arow + 32);

        f32x4 acc[4];
        #pragma unroll
        for (int tile = 0; tile < 4; ++tile) {
            f32x4 z = {0.f, 0.f, 0.f, 0.f};
            z = __builtin_amdgcn_mfma_f32_16x16x32_bf16(a0, bfrag[tile * 2 + 0], z, 0, 0, 0);
            z = __builtin_amdgcn_mfma_f32_16x16x32_bf16(a1, bfrag[tile * 2 + 1], z, 0, 0, 0);
            acc[tile] = z;
        }

        // epilogue: this lane owns edges m = quad*4 + r (r=0..3), dims tile*16+c
        int dstm[4]; float samem[4]; float exr[4];
        float xtv[4][4];
        #pragma unroll
        for (int r = 0; r < 4; ++r) {
            int m = quad * 4 + r;
            dstm[r] = __shfl(dstL, m);
            float tm = __shfl(tL, m);
            samem[r] = __shfl(sameL, m);
            const float* qsel = (samem[r] > 0.5f) ? qks : qkd;
            float p = 0.f;
            #pragma unroll
            for (int tile = 0; tile < 4; ++tile) {
                float v = acc[tile][r] + fmaf(tm, w64c[tile], btc[tile]);
                v = gelu_exact(v);
                float ph = tm * dva[tile];
                v += use_cos ? cosf(ph) : sinf(ph);
                xtv[r][tile] = v;
                p = fmaf(v, qsel[(long)dstm[r] * D + tile * 16 + c], p);
            }
            // reduce p over the 16 lanes of this group
            #pragma unroll
            for (int o = 1; o < 16; o <<= 1) p += __shfl_xor(p, o);
            float bqv = (samem[r] > 0.5f) ? bqs[dstm[r]] : bqd[dstm[r]];
            exr[r] = expf((p + bqv) * 0.125f);
        }

        #pragma unroll
        for (int r = 0; r < 4; ++r) {
            long me = e0 + quad * 4 + r;
            if (me < E) {
                float ex = exr[r];
                float* Asel = (samem[r] > 0.5f) ? As : Ad;
                #pragma unroll
                for (int tile = 0; tile < 4; ++tile)
                    atomicAdd(&Asel[(long)dstm[r] * D + tile * 16 + c], ex * xtv[r][tile]);
                if (c == 0)
                    atomicAdd((samem[r] > 0.5f) ? &den_s[dstm[r]] : &den_d[dstm[r]], ex);
            }
        }
    }
}

// K3: per node: aggr = (As/den)@Wvs^T + (den_s/den)*bvs + (Ad/den)@Wvd^T + (den_d/den)*bvd
//     out = x + gelu(aggr)
__global__ __launch_bounds__(256) void node_post(
    const float* __restrict__ x,
    const float* __restrict__ Wvs, const float* __restrict__ bvs,
    const float* __restrict__ Wvd, const float* __restrict__ bvd,
    const float* __restrict__ As, const float* __restrict__ Ad,
    const float* __restrict__ den_s, const float* __restrict__ den_d,
    float* __restrict__ out, int N)
{
    __shared__ float WvsT[64 * 65];
    __shared__ float WvdT[64 * 65];
    for (int idx = threadIdx.x; idx < 4096; idx += 256) {
        int i = idx >> 6, j = idx & 63;
        WvsT[j * 65 + i] = Wvs[idx];
        WvdT[j * 65 + i] = Wvd[idx];
    }
    __syncthreads();
    const int lane = threadIdx.x & 63;
    const int wave = blockIdx.x * (blockDim.x >> 6) + (threadIdx.x >> 6);
    const int nwaves = gridDim.x * (blockDim.x >> 6);
    const float bvsv = bvs[lane], bvdv = bvd[lane];

    for (int n = wave; n < N; n += nwaves) {
        float dsv = den_s[n], ddv = den_d[n];
        float inv = 1.0f / (dsv + ddv + 1e-16f);
        float as = As[(long)n * D + lane] * inv;
        float ad = Ad[(long)n * D + lane] * inv;
        float acc = bvsv * (dsv * inv) + bvdv * (ddv * inv);
        #pragma unroll
        for (int j = 0; j < 64; ++j) {
            acc = fmaf(bcast(as, j), WvsT[j * 65 + lane], acc);
            acc = fmaf(bcast(ad, j), WvdT[j * 65 + lane], acc);
        }
        out[(long)n * D + lane] = x[(long)n * D + lane] + gelu_exact(acc);
    }
}

extern "C" void kernel_launch(void* const* d_in, const int* in_sizes, int n_in,
                              void* d_out, int out_size, void* d_ws, size_t ws_size,
                              hipStream_t stream) {
    const float* x        = (const float*)d_in[0];
    const int*   ei       = (const int*)d_in[1];
    const float* et       = (const float*)d_in[2];
    // d_in[3] = x_time (unused by the reference)
    const float* esame    = (const float*)d_in[4];
    const float* ln_gamma = (const float*)d_in[5];
    const float* ln_beta  = (const float*)d_in[6];
    const float* Wt  = (const float*)d_in[7];
    const float* bt  = (const float*)d_in[8];
    const float* Wq  = (const float*)d_in[9];
    const float* bq  = (const float*)d_in[10];
    const float* Wks = (const float*)d_in[11];
    const float* bks = (const float*)d_in[12];
    const float* Wkd = (const float*)d_in[13];
    const float* bkd = (const float*)d_in[14];
    const float* Wvs = (const float*)d_in[15];
    const float* bvs = (const float*)d_in[16];
    const float* Wvd = (const float*)d_in[17];
    const float* bvd = (const float*)d_in[18];
    float* out = (float*)d_out;

    const int N = in_sizes[0] / D;       // 50000
    const int E = in_sizes[2];           // 800000

    float* w = (float*)d_ws;
    float* qks  = w; w += (long)N * D;
    float* qkd  = w; w += (long)N * D;
    float* bqs  = w; w += N;
    float* bqd  = w; w += N;
    float* As   = w; w += (long)N * D;
    float* Ad   = w; w += (long)N * D;
    float* dens = w; w += N;
    float* dend = w; w += N;
    unsigned short* xnb = (unsigned short*)w; w += (long)N * D / 2;
    unsigned short* WtB = (unsigned short*)w; w += 4096 / 2;

    // zero the accumulators (As, Ad, dens, dend are contiguous)
    hipMemsetAsync(As, 0, ((size_t)N * D * 2 + (size_t)N * 2) * sizeof(float), stream);

    prep_wt<<<1, 64, 0, stream>>>(Wt, WtB);
    node_pre<<<512, 256, 0, stream>>>(x, ln_gamma, ln_beta, Wq, bq, Wks, bks, Wkd, bkd,
                                      xnb, qks, qkd, bqs, bqd, N);
    edge_pass<<<2048, 256, 0, stream>>>(ei, et, esame, xnb, WtB, Wt, bt, qks, qkd, bqs, bqd,
                                        As, Ad, dens, dend, E);
    node_post<<<512, 256, 0, stream>>>(x, Wvs, bvs, Wvd, bvd, As, Ad, dens, dend, out, N);
}